// Round 9
// baseline (401.195 us; speedup 1.0000x reference)
//
#include <hip/hip_runtime.h>
#include <cmath>

#define BB 2
#define SS 2048
#define DD 1024
#define HH 16
#define HDD 64
#define MM (BB * SS)
#define BH (BB * HH)

typedef _Float16 f16;
typedef _Float16 f16x2 __attribute__((ext_vector_type(2)));
typedef _Float16 f16x4 __attribute__((ext_vector_type(4)));
typedef _Float16 f16x8 __attribute__((ext_vector_type(8)));
typedef float f32x4 __attribute__((ext_vector_type(4)));
typedef float f32x16 __attribute__((ext_vector_type(16)));
typedef unsigned int u32x4 __attribute__((ext_vector_type(4)));

#define MFMA(A, B, C) __builtin_amdgcn_mfma_f32_16x16x32_f16(A, B, C, 0, 0, 0)
#define MFMA32(A, B, C) __builtin_amdgcn_mfma_f32_32x32x16_f16(A, B, C, 0, 0, 0)

__device__ __forceinline__ void gload16(const void* g, void* l) {
    __builtin_amdgcn_global_load_lds(
        (const __attribute__((address_space(1))) void*)g,
        (__attribute__((address_space(3))) void*)l, 16, 0, 0);
}

__device__ __forceinline__ unsigned pk(float a, float b) {
    auto h = __builtin_amdgcn_cvt_pkrtz(a, b);   // __fp16 ext_vector(2)
    return __builtin_bit_cast(unsigned, h);
}

// Build the PV A-fragment (16 consecutive k) from 8 per-lane P values whose
// k-pattern is (r&3)+8*(r>>2)+4*hi. Half-exchange via shfl_xor(32)+select.
// (HW-verified in round 5; permlane variant reverted after NaN in r6/r7.)
__device__ __forceinline__ f16x8 pack8(float p0, float p1, float p2, float p3,
                                       float p4, float p5, float p6, float p7,
                                       int hi) {
    unsigned wa = pk(p0, p1), wa2 = pk(p2, p3);
    unsigned wb = pk(p4, p5), wb2 = pk(p6, p7);
    unsigned xa = __shfl_xor(wa, 32), xa2 = __shfl_xor(wa2, 32);
    unsigned xb = __shfl_xor(wb, 32), xb2 = __shfl_xor(wb2, 32);
    unsigned w0 = hi ? xb : wa;
    unsigned w1 = hi ? xb2 : wa2;
    unsigned w2 = hi ? wb : xa;
    unsigned w3 = hi ? wb2 : xa2;
    u32x4 w = {w0, w1, w2, w3};
    return __builtin_bit_cast(f16x8, w);
}

// ---------------------------------------------------------------------------
// RoPE cos/sin table (fp64 trig to match numpy).
// ---------------------------------------------------------------------------
__global__ __launch_bounds__(256) void k_rope_table(float* __restrict__ cosT,
                                                    float* __restrict__ sinT) {
    int idx = blockIdx.x * 256 + threadIdx.x;
    int s = idx >> 5, j = idx & 31;
    double inv = pow(10000.0, -(double)(2 * j) / 64.0);
    double ang = (double)s * inv;
    cosT[idx] = (float)cos(ang);
    sinT[idx] = (float)sin(ang);
}

// ---------------------------------------------------------------------------
// x (fp32, M x D) -> xb (fp16, same layout)
// ---------------------------------------------------------------------------
__global__ __launch_bounds__(256) void k_cast_x(const float* __restrict__ x,
                                                f16* __restrict__ xb) {
    int i = (blockIdx.x * 256 + threadIdx.x) * 8;
    float4 a = *(const float4*)&x[i];
    float4 b = *(const float4*)&x[i + 4];
    f16x8 o = {(f16)a.x, (f16)a.y, (f16)a.z, (f16)a.w,
               (f16)b.x, (f16)b.y, (f16)b.z, (f16)b.w};
    *(f16x8*)&xb[i] = o;
}

// ---------------------------------------------------------------------------
// W (fp32, K x N) -> Wt (fp16, N x K)  for Wq,Wk,Wv,Wo (z = 0..3)
// ---------------------------------------------------------------------------
__global__ __launch_bounds__(256) void k_wcast(const float* __restrict__ Wq,
        const float* __restrict__ Wk, const float* __restrict__ Wv,
        const float* __restrict__ Wo, f16* __restrict__ WtAll) {
    const int z = blockIdx.z;
    const float* __restrict__ src = (z == 0) ? Wq : (z == 1) ? Wk
                                   : (z == 2) ? Wv : Wo;
    f16* __restrict__ dst = WtAll + (size_t)z * DD * DD;
    const int kk0 = blockIdx.x * 64, nn0 = blockIdx.y * 64;
    __shared__ float t[64][65];
    const int tid = threadIdx.x;
    const int rr = tid >> 4, c4 = (tid & 15) * 4;
#pragma unroll
    for (int p = 0; p < 4; ++p) {
        float4 v = *(const float4*)&src[(size_t)(kk0 + p * 16 + rr) * DD + nn0 + c4];
        t[p * 16 + rr][c4 + 0] = v.x; t[p * 16 + rr][c4 + 1] = v.y;
        t[p * 16 + rr][c4 + 2] = v.z; t[p * 16 + rr][c4 + 3] = v.w;
    }
    __syncthreads();
#pragma unroll
    for (int p = 0; p < 4; ++p) {
        int n = p * 16 + rr;
        f16x4 o = {(f16)t[c4 + 0][n], (f16)t[c4 + 1][n],
                   (f16)t[c4 + 2][n], (f16)t[c4 + 3][n]};
        *(f16x4*)&dst[(size_t)(nn0 + n) * DD + kk0 + c4] = o;
    }
}

// ---------------------------------------------------------------------------
// QKV GEMM (fp16 MFMA, 128x128 tile, BK=32, global_load_lds staging).
// Epilogue: RoPE (Q,K) + store (B,H,S,HD); K row norms (fp32 -> f16 array).
// ---------------------------------------------------------------------------
__global__ __launch_bounds__(256) void k_qkv(const f16* __restrict__ xb,
        const f16* __restrict__ WtAll,
        const float* __restrict__ cosT, const float* __restrict__ sinT,
        f16* __restrict__ Qh, f16* __restrict__ Kh, f16* __restrict__ Vh,
        f16* __restrict__ knh) {
    const int z = blockIdx.z;
    const f16* __restrict__ Wt = WtAll + (size_t)z * DD * DD;
    f16* __restrict__ dst = (z == 0) ? Qh : (z == 1) ? Kh : Vh;
    const int m0 = blockIdx.x * 128;
    const int n0 = blockIdx.y * 128;
    __shared__ f16 As[128 * 32];
    __shared__ f16 Bs[128 * 32];
    const int tid = threadIdx.x;
    const int wv = tid >> 6, ln = tid & 63;
    const int wm = wv >> 1, wn = wv & 1;
    const int lg = ln >> 4, lr = ln & 15;
    f32x4 acc[4][4] = {};
    for (int k0 = 0; k0 < DD; k0 += 32) {
        __syncthreads();
#pragma unroll
        for (int u = 0; u < 2; ++u) {
            int e = u * 2048 + wv * 512 + ln * 8;
            int r = e >> 5, c = e & 31;
            gload16(&xb[(size_t)(m0 + r) * DD + k0 + c], &As[e]);
            gload16(&Wt[(size_t)(n0 + r) * DD + k0 + c], &Bs[e]);
        }
        __syncthreads();
        f16x8 af[4], bf[4];
#pragma unroll
        for (int mt = 0; mt < 4; ++mt)
            af[mt] = *(const f16x8*)&As[(wm * 64 + mt * 16 + lr) * 32 + lg * 8];
#pragma unroll
        for (int nt = 0; nt < 4; ++nt)
            bf[nt] = *(const f16x8*)&Bs[(wn * 64 + nt * 16 + lr) * 32 + lg * 8];
#pragma unroll
        for (int mt = 0; mt < 4; ++mt)
#pragma unroll
            for (int nt = 0; nt < 4; ++nt)
                acc[mt][nt] = MFMA(af[mt], bf[nt], acc[mt][nt]);
    }
    const bool isv = (z == 2);
#pragma unroll
    for (int mt = 0; mt < 4; ++mt) {
        float nsum[4] = {0.f, 0.f, 0.f, 0.f};
#pragma unroll
        for (int reg = 0; reg < 4; ++reg) {
            int gr = m0 + wm * 64 + mt * 16 + lg * 4 + reg;
            int b = gr >> 11, s = gr & (SS - 1);
#pragma unroll
            for (int nt = 0; nt < 4; ++nt) {
                int gc = n0 + wn * 64 + nt * 16 + lr;
                int h = gc >> 6, d = gc & 63;
                float v = acc[mt][nt][reg];
                if (!isv) {
                    float p = __shfl_xor(v, 1);
                    int pr = d >> 1;
                    float cz = cosT[s * 32 + pr], sz = sinT[s * 32 + pr];
                    if ((lr & 1) == 0) {
                        float oe = v * cz - p * sz;
                        float oo = v * sz + p * cz;
                        f16x2 st; st[0] = (f16)oe; st[1] = (f16)oo;
                        *(f16x2*)&dst[(((size_t)b * HH + h) * SS + s) * HDD + d] = st;
                        if (z == 1) nsum[reg] += oe * oe + oo * oo;
                    }
                } else {
                    dst[(((size_t)b * HH + h) * SS + s) * HDD + d] = (f16)v;
                }
            }
        }
        if (z == 1) {
#pragma unroll
            for (int reg = 0; reg < 4; ++reg) {
                float ns = nsum[reg];
                ns += __shfl_xor(ns, 1); ns += __shfl_xor(ns, 2);
                ns += __shfl_xor(ns, 4); ns += __shfl_xor(ns, 8);
                if (lr == 0) {
                    int gr = m0 + wm * 64 + mt * 16 + lg * 4 + reg;
                    int b = gr >> 11, s = gr & (SS - 1);
                    int h = (n0 + wn * 64) >> 6;
                    knh[((size_t)b * HH + h) * SS + s] = (f16)ns;
                }
            }
        }
    }
}

// ---------------------------------------------------------------------------
// Vh (B,H,S,HD) -> Vt (B,H,HD,S)
// ---------------------------------------------------------------------------
__global__ __launch_bounds__(256) void k_vt(const f16* __restrict__ Vh,
                                            f16* __restrict__ Vt) {
    const int s0 = blockIdx.x * 64;
    const int bh = blockIdx.y;
    __shared__ f16 t[64][80];
    const int tid = threadIdx.x;
    const int sr = tid >> 3, d0 = (tid & 7) * 8;
#pragma unroll
    for (int p = 0; p < 2; ++p) {
        f16x8 v = *(const f16x8*)&Vh[((size_t)bh * SS + s0 + p * 32 + sr) * HDD + d0];
#pragma unroll
        for (int j = 0; j < 8; ++j) t[d0 + j][p * 32 + sr] = v[j];
    }
    __syncthreads();
    const int dr = tid >> 3, s4 = (tid & 7) * 8;
#pragma unroll
    for (int p = 0; p < 2; ++p) {
        f16x8 o = *(const f16x8*)&t[p * 32 + dr][s4];
        *(f16x8*)&Vt[((size_t)bh * HDD + p * 32 + dr) * SS + s0 + s4] = o;
    }
}

// ---------------------------------------------------------------------------
// Yat attention, swapped-QK^T 32x32x16, 4-way k-split per block + LDS merge.
// Round-5-proven shuffle forms; ONLY new change: f16 normalized merge buffer
// (o_i/l_i bounded by max|v|, f16-safe) => LDS 35.8 -> 17.9 KB, 8 blocks/CU.
// ---------------------------------------------------------------------------
__global__ __launch_bounds__(256, 6) void k_attn(const f16* __restrict__ Qh,
        const f16* __restrict__ Kh, const f16* __restrict__ Vt,
        const f16* __restrict__ knh,
        const float* __restrict__ alpha, f16* __restrict__ AO) {
    const int tid = threadIdx.x;
    const int wv = tid >> 6, ln = tid & 63;
    const int lq = ln & 31, hi = ln >> 5;
    const int blk = blockIdx.x;
    const int bh = blk & (BH - 1);
    const int qb = (SS / 32 - 1) - (blk >> 5);     // longest first
    const int q0 = qb * 32;
    const float scl = powf(8.0f / logf(65.0f), alpha[0]);
    const f16* __restrict__ Qp = Qh + (size_t)bh * SS * HDD;
    const f16* __restrict__ Kp = Kh + (size_t)bh * SS * HDD;
    const f16* __restrict__ Vp = Vt + (size_t)bh * HDD * SS;
    const f16* __restrict__ knp = knh + (size_t)bh * SS;

    __shared__ f16 oLh[4][32][66];                 // per-wave normalized o
    __shared__ float mlL[4][2][32];

    f16x8 qf[4];
#pragma unroll
    for (int dt = 0; dt < 4; ++dt)
        qf[dt] = *(const f16x8*)&Qp[(size_t)(q0 + lq) * HDD + dt * 16 + hi * 8];
    float qn = 0.f;
#pragma unroll
    for (int dt = 0; dt < 4; ++dt)
#pragma unroll
        for (int j = 0; j < 8; ++j) {
            float v = (float)qf[dt][j];
            qn = fmaf(v, v, qn);
        }
    qn += __shfl_xor(qn, 32);
    const float qnl = qn + 1e-5f;                  // eps folded in

    float m_ = -INFINITY, l_ = 0.f;
    f32x16 o0 = {}, o1 = {};
    f16x8 kf[4];

    if (wv < qb) {
        int kb = wv * 32;
#pragma unroll
        for (int dt = 0; dt < 4; ++dt)
            kf[dt] = *(const f16x8*)&Kp[(size_t)(kb + lq) * HDD + dt * 16 + hi * 8];
    }

    auto tile = [&](int kb, bool diag, bool pre, int kbn) {
        // V + kn issued at top (in flight across QK^T + softmax)
        f16x8 vf0 = *(const f16x8*)&Vp[(size_t)lq * SS + kb + hi * 8];
        f16x8 vf1 = *(const f16x8*)&Vp[(size_t)lq * SS + kb + 16 + hi * 8];
        f16x8 vf2 = *(const f16x8*)&Vp[(size_t)(32 + lq) * SS + kb + hi * 8];
        f16x8 vf3 = *(const f16x8*)&Vp[(size_t)(32 + lq) * SS + kb + 16 + hi * 8];
        f16x4 knv[4];
#pragma unroll
        for (int g = 0; g < 4; ++g)
            knv[g] = *(const f16x4*)&knp[kb + 8 * g + 4 * hi];
        f32x16 s = {};
#pragma unroll
        for (int dt = 0; dt < 4; ++dt) s = MFMA32(kf[dt], qf[dt], s);
        if (pre) {   // next-tile K into same regs (in flight across softmax+PV)
#pragma unroll
            for (int dt = 0; dt < 4; ++dt)
                kf[dt] = *(const f16x8*)&Kp[(size_t)(kbn + lq) * HDD + dt * 16 + hi * 8];
        }
#pragma unroll
        for (int r = 0; r < 16; ++r) {
            const int koff = (r & 3) + 8 * (r >> 2) + 4 * hi;
            float qk = s[r];
            float kv = (float)knv[r >> 2][r & 3];
            float d2 = qnl + kv - 2.0f * qk;
            float sc = qk * qk * scl * __builtin_amdgcn_rcpf(d2);
            if (diag && koff > lq) sc = -3.0e38f;
            s[r] = sc;
        }
        float mx = -3.0e38f;
#pragma unroll
        for (int r = 0; r < 16; ++r) mx = fmaxf(mx, s[r]);
        mx = fmaxf(mx, __shfl_xor(mx, 32));
        if (__any(mx > m_ + 8.0f)) {               // T13 defer-rescale
            float mnew = fmaxf(m_, mx);
            float corr = __expf(m_ - mnew);
            m_ = mnew; l_ *= corr;
#pragma unroll
            for (int r = 0; r < 16; ++r) {
                float cr = __shfl(corr, (r & 3) + 8 * (r >> 2) + 4 * hi);
                o0[r] *= cr; o1[r] *= cr;
            }
        }
        float ps = 0.f;
#pragma unroll
        for (int r = 0; r < 16; ++r) {
            float p = __expf(s[r] - m_); s[r] = p; ps += p;
        }
        ps += __shfl_xor(ps, 32);
        l_ += ps;
        f16x8 pa0 = pack8(s[0], s[1], s[2], s[3], s[4], s[5], s[6], s[7], hi);
        f16x8 pa1 = pack8(s[8], s[9], s[10], s[11], s[12], s[13], s[14], s[15], hi);
        o0 = MFMA32(pa0, vf0, o0);
        o0 = MFMA32(pa1, vf1, o0);
        o1 = MFMA32(pa0, vf2, o1);
        o1 = MFMA32(pa1, vf3, o1);
    };

    for (int kt = wv; kt < qb; kt += 4) {
        const bool pre = (kt + 4 < qb);
        tile(kt * 32, false, pre, pre ? (kt + 4) * 32 : 0);
    }
    if ((qb & 3) == wv) {                          // diagonal tile
        int kb = qb * 32;
#pragma unroll
        for (int dt = 0; dt < 4; ++dt)
            kf[dt] = *(const f16x8*)&Kp[(size_t)(kb + lq) * HDD + dt * 16 + hi * 8];
        tile(kb, true, false, 0);
    }

    // ---- per-wave normalize (f16-safe range), then merge 4 flash states ----
    float rl = (l_ > 0.f) ? __builtin_amdgcn_rcpf(l_) : 0.f;
#pragma unroll
    for (int r = 0; r < 16; ++r) {
        int q = (r & 3) + 8 * (r >> 2) + 4 * hi;
        float rr = __shfl(rl, q);
        oLh[wv][q][lq] = (f16)(o0[r] * rr);
        oLh[wv][q][32 + lq] = (f16)(o1[r] * rr);
    }
    if (hi == 0) { mlL[wv][0][lq] = m_; mlL[wv][1][lq] = l_; }
    __syncthreads();
    {
        const int q = tid >> 3, d8 = (tid & 7) * 8;
        float mv[4], lv[4];
#pragma unroll
        for (int i = 0; i < 4; ++i) { mv[i] = mlL[i][0][q]; lv[i] = mlL[i][1][q]; }
        float M = fmaxf(fmaxf(mv[0], mv[1]), fmaxf(mv[2], mv[3]));
        float w4[4], L = 0.f;
#pragma unroll
        for (int i = 0; i < 4; ++i) {
            w4[i] = lv[i] * __expf(mv[i] - M);
            L += w4[i];
        }
        float rL = 1.0f / L;
        float acc[8] = {};
#pragma unroll
        for (int i = 0; i < 4; ++i) {
            f16x8 v8 = *(const f16x8*)&oLh[i][q][d8];
            float wi = w4[i] * rL;
#pragma unroll
            for (int j = 0; j < 8; ++j)
                acc[j] = fmaf((float)v8[j], wi, acc[j]);
        }
        f16x8 st;
#pragma unroll
        for (int j = 0; j < 8; ++j) st[j] = (f16)acc[j];
        *(f16x8*)&AO[((size_t)bh * SS + q0 + q) * HDD + d8] = st;
    }
}

// ---------------------------------------------------------------------------
// out = AO(gathered to (b,s,h*hd)) @ Wo  (fp16 MFMA, fp32 out)
// ---------------------------------------------------------------------------
__global__ __launch_bounds__(256) void k_proj(const f16* __restrict__ AO,
        const f16* __restrict__ Wot, float* __restrict__ out) {
    const int m0 = blockIdx.x * 128;
    const int n0 = blockIdx.y * 128;
    __shared__ f16 As[128 * 32];
    __shared__ f16 Bs[128 * 32];
    const int tid = threadIdx.x;
    const int wv = tid >> 6, ln = tid & 63;
    const int wm = wv >> 1, wn = wv & 1;
    const int lg = ln >> 4, lr = ln & 15;
    f32x4 acc[4][4] = {};
    for (int k0 = 0; k0 < DD; k0 += 32) {
        __syncthreads();
#pragma unroll
        for (int u = 0; u < 2; ++u) {
            int e = u * 2048 + wv * 512 + ln * 8;
            int r = e >> 5, c = e & 31;
            int gm = m0 + r, b = gm >> 11, s = gm & (SS - 1);
            int k = k0 + c, h = k >> 6, d = k & 63;
            gload16(&AO[(((size_t)b * HH + h) * SS + s) * HDD + d], &As[e]);
            gload16(&Wot[(size_t)(n0 + r) * DD + k0 + c], &Bs[e]);
        }
        __syncthreads();
        f16x8 af[4], bf[4];
#pragma unroll
        for (int mt = 0; mt < 4; ++mt)
            af[mt] = *(const f16x8*)&As[(wm * 64 + mt * 16 + lr) * 32 + lg * 8];
#pragma unroll
        for (int nt = 0; nt < 4; ++nt)
            bf[nt] = *(const f16x8*)&Bs[(wn * 64 + nt * 16 + lr) * 32 + lg * 8];
#pragma unroll
        for (int mt = 0; mt < 4; ++mt)
#pragma unroll
            for (int nt = 0; nt < 4; ++nt)
                acc[mt][nt] = MFMA(af[mt], bf[nt], acc[mt][nt]);
    }
#pragma unroll
    for (int mt = 0; mt < 4; ++mt)
#pragma unroll
        for (int reg = 0; reg < 4; ++reg) {
            int gr = m0 + wm * 64 + mt * 16 + lg * 4 + reg;
#pragma unroll
            for (int nt = 0; nt < 4; ++nt) {
                int gc = n0 + wn * 64 + nt * 16 + lr;
                out[(size_t)gr * DD + gc] = acc[mt][nt][reg];
            }
        }
}

extern "C" void kernel_launch(void* const* d_in, const int* in_sizes, int n_in,
                              void* d_out, int out_size, void* d_ws, size_t ws_size,
                              hipStream_t stream) {
    const float* x     = (const float*)d_in[0];
    const float* Wq    = (const float*)d_in[1];
    const float* Wk    = (const float*)d_in[2];
    const float* Wv    = (const float*)d_in[3];
    const float* Wo    = (const float*)d_in[4];
    const float* alpha = (const float*)d_in[5];
    float* out = (float*)d_out;

    float* cosT = (float*)d_ws;
    float* sinT = cosT + SS * 32;
    f16* knh    = (f16*)(sinT + SS * 32);
    f16* xb     = knh + (size_t)BH * SS;
    f16* WtAll  = xb + (size_t)MM * DD;
    f16* Qh     = WtAll + (size_t)4 * DD * DD;
    f16* Kh     = Qh + (size_t)MM * DD;
    f16* Vh     = Kh + (size_t)MM * DD;
    f16* Vt     = Vh + (size_t)MM * DD;
    f16* AO     = Vt + (size_t)MM * DD;
    f16* Wot    = WtAll + (size_t)3 * DD * DD;

    hipLaunchKernelGGL(k_rope_table, dim3(SS * 32 / 256), dim3(256), 0, stream,
                       cosT, sinT);
    hipLaunchKernelGGL(k_cast_x, dim3(MM * DD / (256 * 8)), dim3(256), 0, stream,
                       x, xb);
    hipLaunchKernelGGL(k_wcast, dim3(16, 16, 4), dim3(256), 0, stream,
                       Wq, Wk, Wv, Wo, WtAll);
    hipLaunchKernelGGL(k_qkv, dim3(MM / 128, DD / 128, 3), dim3(256), 0, stream,
                       xb, WtAll, cosT, sinT, Qh, Kh, Vh, knh);
    hipLaunchKernelGGL(k_vt, dim3(SS / 64, BH), dim3(256), 0, stream, Vh, Vt);
    hipLaunchKernelGGL(k_attn, dim3((SS / 32) * BH), dim3(256), 0, stream,
                       Qh, Kh, Vt, knh, alpha, AO);
    hipLaunchKernelGGL(k_proj, dim3(MM / 128, DD / 128), dim3(256), 0, stream,
                       AO, Wot, out);
}